// Round 14
// baseline (315.588 us; speedup 1.0000x reference)
//
#include <hip/hip_runtime.h>

#define HW (512 * 512)
#define QP 260   // pitch (floats): >=256, %8==4 -> phase-B row reads hit disjoint bank quads
#define WN 12288 // 192*64

typedef __bf16 bf16;
typedef __attribute__((ext_vector_type(8))) __bf16 bf16x8;
typedef __attribute__((ext_vector_type(4))) float f32x4;

__device__ __forceinline__ void cvt_split(float f, bf16& h, bf16& l) {
    h = (bf16)f;
    l = (bf16)(f - (float)h);
}

// Precompute: W -> bf16 hi/lo planes in d_ws (48 KB, L2-resident). (verified R8+)
__global__ __launch_bounds__(256) void wcvt_kernel(
    const float* __restrict__ w, bf16* __restrict__ wh, bf16* __restrict__ wl)
{
    const int i = blockIdx.x * 256 + threadIdx.x;
    if (i < WN) {
        bf16 h, l;
        cvt_split(w[i], h, l);
        wh[i] = h;
        wl[i] = l;
    }
}

// R14: 512-thread blocks, TWO windows per block, wave-group g = n>>8 owns window g.
// Per-wave structure is exactly the verified R8 body (X frags 64 VGPR + acc 32 AGPR
// + temps ~= 116 regs <= 128 quantum), so residency can double vs R10's per-thread
// 2-window packing (which needed ~160+ regs -> 256 quantum -> 2 waves/SIMD).
// Schedule per head (2 barriers, R8-proven):
//   A: proj+feat, elu, sums, kf/av writeback (own column); shfl T-reduce; wave fence
//   B: kv partials over own wave's 64 px -> kvp[wg]
//   S3; then wave-LOCAL kv reduce (R12-verified) + D (z/feat/out)  ||  stage(h+1)
//   S4
// Race audit: qk[wg] readers all pre-S3, stage writes post-S3; kvp/tp written pre-S3,
// read pre-S4, next write post-S4; kv_s wave-private segment + lgkm fence.
// No forced reg cap (R4/R5/R9: cap below natural demand => spill traffic).
__global__ __launch_bounds__(512, 2) void lwmsa_kernel(
    const float* __restrict__ x,
    const bf16* __restrict__ wh,
    const bf16* __restrict__ wl,
    float* __restrict__ out)
{
    const int blk  = blockIdx.x;       // 0..2047
    const int b    = blk >> 9;
    const int wrow = (blk >> 4) & 31;
    const int wp   = blk & 15;
    const int n    = threadIdx.x;      // 0..511
    const int wg   = n >> 8;           // window 0/1 (wave-group)
    const int t    = n & 255;          // pixel in window
    const int lane = n & 63;
    const int wv4  = (n >> 6) & 3;     // wave id within window group
    const int gw   = n >> 6;           // global wave id 0..7
    const int c16  = lane & 15;
    const int q4   = lane >> 4;

    const int wcol = wp * 2 + wg;
    const int base = b * (64 * HW) + (wrow * 16 + (t >> 4)) * 512 + wcol * 16 + (t & 15);
    const int xwin = b * (64 * HW) + (wrow * 16) * 512 + wcol * 16;

    __shared__ float qk[2][24 * QP];   // per window: q rows 0-7, k 8-15, v 16-23
    __shared__ float kvp[2][256];      // per window: per-wave kv partials
    __shared__ float kv_s[8][64];      // per-wave kv broadcast segments
    __shared__ float tp[2][4];         // per window: k-sum partials per wave

    // ---- A-fragments (X) for OWN window only: 64 VGPR ----
    bf16x8 ah[2][4], al[2][4];         // [ks][mt]
    #pragma unroll
    for (int ks = 0; ks < 2; ++ks)
        #pragma unroll
        for (int mt = 0; mt < 4; ++mt) {
            const int row = wv4 * 4 + mt;
            const float* xp = x + xwin + row * 512 + c16 + (ks * 32 + q4 * 8) * HW;
            #pragma unroll
            for (int j = 0; j < 8; ++j) {
                bf16 h, l;
                cvt_split(xp[j * HW], h, l);
                ah[ks][mt][j] = h;
                al[ks][mt][j] = l;
            }
        }

    // ---- per-head MFMA + stage own window's 24 rows ----
    auto mfma_stage = [&](int hh) {
        f32x4 acc[4][2];
        #pragma unroll
        for (int mt = 0; mt < 4; ++mt)
            #pragma unroll
            for (int nt = 0; nt < 2; ++nt)
                acc[mt][nt] = (f32x4){0.f, 0.f, 0.f, 0.f};

        #pragma unroll
        for (int ks = 0; ks < 2; ++ks) {
            #pragma unroll
            for (int nt = 0; nt < 2; ++nt) {
                const int ml   = nt * 16 + c16;                 // 0..31; valid < 24
                const int grow = (ml < 24) ? ((ml >> 3) * 64 + hh * 8 + (ml & 7))
                                           : (hh * 8);          // in-bounds dummy
                const int off  = grow * 64 + ks * 32 + q4 * 8;
                const bf16x8 bh = *(const bf16x8*)&wh[off];
                const bf16x8 bl = *(const bf16x8*)&wl[off];
                #pragma unroll
                for (int mt = 0; mt < 4; ++mt) {
                    acc[mt][nt] = __builtin_amdgcn_mfma_f32_16x16x32_bf16(ah[ks][mt], bh, acc[mt][nt], 0, 0, 0);
                    acc[mt][nt] = __builtin_amdgcn_mfma_f32_16x16x32_bf16(al[ks][mt], bh, acc[mt][nt], 0, 0, 0);
                    acc[mt][nt] = __builtin_amdgcn_mfma_f32_16x16x32_bf16(ah[ks][mt], bl, acc[mt][nt], 0, 0, 0);
                }
            }
        }

        // D: lane holds qkv-row ml=nt*16+c16 at px=(wv4*4+mt)*16+q4*4+reg
        #pragma unroll
        for (int nt = 0; nt < 2; ++nt) {
            const int ml = nt * 16 + c16;
            if (ml < 24) {
                #pragma unroll
                for (int mt = 0; mt < 4; ++mt) {
                    const int px = (wv4 * 4 + mt) * 16 + q4 * 4;
                    *(float4*)&qk[wg][ml * QP + px] = *(float4*)&acc[mt][nt];
                }
            }
        }
    };

    float feat[8];
    #pragma unroll
    for (int d = 0; d < 8; ++d) feat[d] = 0.f;

    mfma_stage(0);
    __syncthreads();  // S_init: head-0 projections visible

    for (int h = 0; h < 8; ++h) {
        // ---- phase A: proj+feat, elu1, row sums; write kf/av back (own column) ----
        float qf[8];
        float Sq = 0.f, tpart = 0.f;
        #pragma unroll
        for (int d = 0; d < 8; ++d) {
            const float aq = qk[wg][d * QP + t]        + feat[d];
            const float ak = qk[wg][(8 + d) * QP + t]  + feat[d];
            const float av = qk[wg][(16 + d) * QP + t] + feat[d];
            qf[d] = aq > 0.f ? aq + 1.f : __expf(aq);
            const float kf = ak > 0.f ? ak + 1.f : __expf(ak);
            Sq    += qf[d];
            tpart += kf;
            qk[wg][(8 + d) * QP + t]  = kf;
            qk[wg][(16 + d) * QP + t] = av;
        }

        #pragma unroll
        for (int off = 1; off < 64; off <<= 1)
            tpart += __shfl_xor(tpart, off, 64);
        if (lane == 0) tp[wg][wv4] = tpart;

        // wave-internal handoff: B reads only this wave's 64 columns (R8-verified)
        asm volatile("s_waitcnt lgkmcnt(0)" ::: "memory");

        // ---- phase B: kv partials over this wave's 64 px ----
        {
            const float4* kr = (const float4*)(qk[wg] + (8 + (lane >> 3)) * QP + wv4 * 64);
            const float4* vr = (const float4*)(qk[wg] + (16 + (lane & 7)) * QP + wv4 * 64);
            float s0 = 0.f, s1 = 0.f, s2 = 0.f, s3 = 0.f;
            #pragma unroll
            for (int j = 0; j < 16; ++j) {
                const float4 kk = kr[j];
                const float4 vv = vr[j];
                s0 = fmaf(kk.x, vv.x, s0);
                s1 = fmaf(kk.y, vv.y, s1);
                s2 = fmaf(kk.z, vv.z, s2);
                s3 = fmaf(kk.w, vv.w, s3);
            }
            kvp[wg][wv4 * 64 + lane] = (s0 + s1) + (s2 + s3);
        }

        __syncthreads();  // S3: kvp + tp visible; all qk readers done -> restage allowed

        // ---- wave-local kv reduce (R12-verified) + phase D, overlapped with stage ----
        {
            const float kvsum = (kvp[wg][lane] + kvp[wg][64 + lane]) +
                                (kvp[wg][128 + lane] + kvp[wg][192 + lane]);
            kv_s[gw][lane] = kvsum;   // kv[lane>>3][lane&7], wave-private segment
        }
        asm volatile("s_waitcnt lgkmcnt(0)" ::: "memory");

        const float T  = ((tp[wg][0] + tp[wg][1]) + (tp[wg][2] + tp[wg][3])) + 8.0f * 1e-6f;
        const float zi = 1.0f / (Sq * T);

        float ft[8];
        #pragma unroll
        for (int d = 0; d < 8; ++d) ft[d] = 0.f;
        #pragma unroll
        for (int d = 0; d < 8; ++d) {
            const float qd = qf[d];
            const float4 a  = ((const float4*)(&kv_s[gw][d * 8]))[0];
            const float4 bb = ((const float4*)(&kv_s[gw][d * 8]))[1];
            ft[0] = fmaf(qd, a.x,  ft[0]);
            ft[1] = fmaf(qd, a.y,  ft[1]);
            ft[2] = fmaf(qd, a.z,  ft[2]);
            ft[3] = fmaf(qd, a.w,  ft[3]);
            ft[4] = fmaf(qd, bb.x, ft[4]);
            ft[5] = fmaf(qd, bb.y, ft[5]);
            ft[6] = fmaf(qd, bb.z, ft[6]);
            ft[7] = fmaf(qd, bb.w, ft[7]);
        }
        #pragma unroll
        for (int d = 0; d < 8; ++d) {
            feat[d] = ft[d] * zi;
            out[base + (h * 8 + d) * HW] = feat[d];
        }

        if (h < 7)
            mfma_stage(h + 1);   // overlaps phase D's VALU; qk readers all passed S3

        __syncthreads();  // S4: next head's projections visible
    }
}

extern "C" void kernel_launch(void* const* d_in, const int* in_sizes, int n_in,
                              void* d_out, int out_size, void* d_ws, size_t ws_size,
                              hipStream_t stream) {
    const float* x  = (const float*)d_in[0];
    const float* w  = (const float*)d_in[1];
    float* out      = (float*)d_out;
    bf16* wh = (bf16*)d_ws;
    bf16* wl = wh + WN;
    wcvt_kernel<<<dim3((WN + 255) / 256), dim3(256), 0, stream>>>(w, wh, wl);
    lwmsa_kernel<<<dim3(2048), dim3(512), 0, stream>>>(x, wh, wl, out);
}

// Round 15
// 236.022 us; speedup vs baseline: 1.3371x; 1.3371x over previous
//
#include <hip/hip_runtime.h>

#define HW (512 * 512)
#define QP 260   // pitch (floats): >=256, %4==0 (b128-clean), %32==4 staggers row banks
#define WN 12288 // 192*64

typedef __bf16 bf16;
typedef __attribute__((ext_vector_type(8))) __bf16 bf16x8;
typedef __attribute__((ext_vector_type(4))) float f32x4;

__device__ __forceinline__ void cvt_split(float f, bf16& h, bf16& l) {
    h = (bf16)f;
    l = (bf16)(f - (float)h);
}

// pack f32 -> u32 = (bf16 hi << 16) | bf16 lo. hi = truncated top-16 bits (exact bf16),
// lo = RNE(x - hi). 3-term MFMA with these matches the verified projection scheme.
__device__ __forceinline__ unsigned int pack_hl(float x) {
    const unsigned int hx = __float_as_uint(x) & 0xFFFF0000u;
    const float lof = x - __uint_as_float(hx);
    const bf16 lb = (bf16)lof;
    return hx | (unsigned int)__builtin_bit_cast(unsigned short, lb);
}

// unpack 8 packed u32 (px-consecutive) into hi-plane and lo-plane bf16x8 fragments.
// v_perm: __builtin_amdgcn_perm(S0, S1, sel); sel codes 0-3 pick S1 bytes, 4-7 S0 bytes.
__device__ __forceinline__ void unpack8(const uint4 a0, const uint4 a1,
                                        bf16x8& hv, bf16x8& lv) {
    union { unsigned int u[4]; bf16x8 v; } H, L;
    H.u[0] = __builtin_amdgcn_perm(a0.y, a0.x, 0x07060302u);
    L.u[0] = __builtin_amdgcn_perm(a0.y, a0.x, 0x05040100u);
    H.u[1] = __builtin_amdgcn_perm(a0.w, a0.z, 0x07060302u);
    L.u[1] = __builtin_amdgcn_perm(a0.w, a0.z, 0x05040100u);
    H.u[2] = __builtin_amdgcn_perm(a1.y, a1.x, 0x07060302u);
    L.u[2] = __builtin_amdgcn_perm(a1.y, a1.x, 0x05040100u);
    H.u[3] = __builtin_amdgcn_perm(a1.w, a1.z, 0x07060302u);
    L.u[3] = __builtin_amdgcn_perm(a1.w, a1.z, 0x05040100u);
    hv = H.v; lv = L.v;
}

// Precompute: W -> bf16 hi/lo planes in d_ws (48 KB, L2-resident). (verified R8+)
__global__ __launch_bounds__(256) void wcvt_kernel(
    const float* __restrict__ w, bf16* __restrict__ wh, bf16* __restrict__ wl)
{
    const int i = blockIdx.x * 256 + threadIdx.x;
    if (i < WN) {
        bf16 h, l;
        cvt_split(w[i], h, l);
        wh[i] = h;
        wl[i] = l;
    }
}

// R15 = R10 (2 windows/block, best @256us) with phase B moved to the MATRIX pipe.
// Diagnosis: R10 is LDS-bandwidth-bound (~1460 LDS-pipe cyc/wave-head; 64 b128 phase-B
// reads = 53%). Fix: phase A writes kf/av as hi/lo-packed bf16 u32 at the SAME own-column
// addresses (same write cost); kv[d][c] = sum_px kf[d][px]*av[c][px] becomes a per-wave
// 16x16x(2x32) MFMA: A-frag row=c16 (kf row d), B-frag col=c16 (av row c), k=q4*8+j (px);
// D col=c16=c, row=q4*4+reg=d -> kvp in the EXISTING layout; reduce/phase D unchanged.
// LDS/wave-head: 1460 -> ~920 cyc. No forced reg cap (R4/R5/R9: cap => spill).
__global__ __launch_bounds__(256, 2) void lwmsa_kernel(
    const float* __restrict__ x,
    const bf16* __restrict__ wh,
    const bf16* __restrict__ wl,
    float* __restrict__ out)
{
    const int blk  = blockIdx.x;       // 0..2047
    const int b    = blk >> 9;
    const int wrow = (blk >> 4) & 31;
    const int wp   = blk & 15;         // col pair: wcol = 2*wp + w
    const int n    = threadIdx.x;      // 0..255 = pixel in window
    const int lane = n & 63;
    const int wvid = n >> 6;           // wave 0..3
    const int c16  = lane & 15;
    const int q4   = lane >> 4;

    __shared__ float qk[2][24 * QP];   // per window: q rows 0-7, k 8-15, v 16-23
    __shared__ float kvp[2][256];      // per window: per-wave kv partials [wave][d*8+c]
    __shared__ float kv_s[2][64];
    __shared__ float tp[2][2][4];      // [win][parity][wave]

    int base[2], xwin[2];
    #pragma unroll
    for (int w = 0; w < 2; ++w) {
        const int wcol = wp * 2 + w;
        base[w] = b * (64 * HW) + (wrow * 16 + (n >> 4)) * 512 + wcol * 16 + (n & 15);
        xwin[w] = b * (64 * HW) + (wrow * 16) * 512 + wcol * 16;
    }

    // ---- A-fragments (X) for both windows, hi/lo, global -> registers ----
    bf16x8 ah[2][2][4], al[2][2][4];   // [win][ks][mt]
    #pragma unroll
    for (int w = 0; w < 2; ++w)
        #pragma unroll
        for (int ks = 0; ks < 2; ++ks)
            #pragma unroll
            for (int mt = 0; mt < 4; ++mt) {
                const int row = wvid * 4 + mt;
                const float* xp = x + xwin[w] + row * 512 + c16 + (ks * 32 + q4 * 8) * HW;
                #pragma unroll
                for (int j = 0; j < 8; ++j) {
                    bf16 h, l;
                    cvt_split(xp[j * HW], h, l);
                    ah[w][ks][mt][j] = h;
                    al[w][ks][mt][j] = l;
                }
            }

    // ---- per-head MFMA + stage into qk[w]: 24 rows (q0-7,k8-15,v16-23) ----
    auto mfma_stage = [&](int w, int hh) {
        f32x4 acc[4][2];
        #pragma unroll
        for (int mt = 0; mt < 4; ++mt)
            #pragma unroll
            for (int nt = 0; nt < 2; ++nt)
                acc[mt][nt] = (f32x4){0.f, 0.f, 0.f, 0.f};

        #pragma unroll
        for (int ks = 0; ks < 2; ++ks) {
            #pragma unroll
            for (int nt = 0; nt < 2; ++nt) {
                const int ml   = nt * 16 + c16;                 // 0..31; valid < 24
                const int grow = (ml < 24) ? ((ml >> 3) * 64 + hh * 8 + (ml & 7))
                                           : (hh * 8);          // in-bounds dummy
                const int off  = grow * 64 + ks * 32 + q4 * 8;
                const bf16x8 bh = *(const bf16x8*)&wh[off];
                const bf16x8 bl = *(const bf16x8*)&wl[off];
                #pragma unroll
                for (int mt = 0; mt < 4; ++mt) {
                    acc[mt][nt] = __builtin_amdgcn_mfma_f32_16x16x32_bf16(ah[w][ks][mt], bh, acc[mt][nt], 0, 0, 0);
                    acc[mt][nt] = __builtin_amdgcn_mfma_f32_16x16x32_bf16(al[w][ks][mt], bh, acc[mt][nt], 0, 0, 0);
                    acc[mt][nt] = __builtin_amdgcn_mfma_f32_16x16x32_bf16(ah[w][ks][mt], bl, acc[mt][nt], 0, 0, 0);
                }
            }
        }

        #pragma unroll
        for (int nt = 0; nt < 2; ++nt) {
            const int ml = nt * 16 + c16;
            if (ml < 24) {
                #pragma unroll
                for (int mt = 0; mt < 4; ++mt) {
                    const int px = (wvid * 4 + mt) * 16 + q4 * 4;
                    *(float4*)&qk[w][ml * QP + px] = *(float4*)&acc[mt][nt];
                }
            }
        }
    };

    float feat[2][8];
    #pragma unroll
    for (int w = 0; w < 2; ++w)
        #pragma unroll
        for (int d = 0; d < 8; ++d) feat[w][d] = 0.f;

    mfma_stage(0, 0);
    mfma_stage(1, 0);
    __syncthreads();  // S_init: head-0 projections of both windows visible

    for (int h = 0; h < 8; ++h) {
        // ---- phase A (x2): proj+feat, elu1, sums; write PACKED kf/av (own column) ----
        float qf[2][8], Sq[2], tpart[2];
        #pragma unroll
        for (int w = 0; w < 2; ++w) {
            Sq[w] = 0.f; tpart[w] = 0.f;
            unsigned int* qku = (unsigned int*)qk[w];
            #pragma unroll
            for (int d = 0; d < 8; ++d) {
                const float aq = qk[w][d * QP + n]        + feat[w][d];
                const float ak = qk[w][(8 + d) * QP + n]  + feat[w][d];
                const float av = qk[w][(16 + d) * QP + n] + feat[w][d];
                qf[w][d] = aq > 0.f ? aq + 1.f : __expf(aq);
                const float kf = ak > 0.f ? ak + 1.f : __expf(ak);
                Sq[w]    += qf[w][d];
                tpart[w] += kf;
                qku[(8 + d) * QP + n]  = pack_hl(kf);   // own column: no hazard
                qku[(16 + d) * QP + n] = pack_hl(av);
            }
        }

        #pragma unroll
        for (int off = 1; off < 64; off <<= 1) {
            tpart[0] += __shfl_xor(tpart[0], off, 64);
            tpart[1] += __shfl_xor(tpart[1], off, 64);
        }
        if (lane == 0) {
            tp[0][h & 1][wvid] = tpart[0];
            tp[1][h & 1][wvid] = tpart[1];
        }

        // wave-internal handoff: phase B reads only this wave's 64 columns (R8-verified)
        asm volatile("s_waitcnt lgkmcnt(0)" ::: "memory");

        // ---- phase B (x2): kv via MFMA over this wave's 64 px ----
        #pragma unroll
        for (int w = 0; w < 2; ++w) {
            const unsigned int* qku = (const unsigned int*)qk[w];
            f32x4 kvacc = (f32x4){0.f, 0.f, 0.f, 0.f};
            const int arow = 8  + (c16 & 7);    // kf row d (rows 8-15 duplicate 0-7)
            const int brow = 16 + (c16 & 7);    // av row c
            #pragma unroll
            for (int s = 0; s < 2; ++s) {
                const int off = wvid * 64 + s * 32 + q4 * 8;
                const uint4 pa0 = *(const uint4*)(qku + arow * QP + off);
                const uint4 pa1 = *(const uint4*)(qku + arow * QP + off + 4);
                const uint4 pb0 = *(const uint4*)(qku + brow * QP + off);
                const uint4 pb1 = *(const uint4*)(qku + brow * QP + off + 4);
                bf16x8 kah, kal, bvh, bvl;
                unpack8(pa0, pa1, kah, kal);
                unpack8(pb0, pb1, bvh, bvl);
                kvacc = __builtin_amdgcn_mfma_f32_16x16x32_bf16(kah, bvh, kvacc, 0, 0, 0);
                kvacc = __builtin_amdgcn_mfma_f32_16x16x32_bf16(kah, bvl, kvacc, 0, 0, 0);
                kvacc = __builtin_amdgcn_mfma_f32_16x16x32_bf16(kal, bvh, kvacc, 0, 0, 0);
            }
            // D: col=c16=c, row=q4*4+reg=d; valid 8x8 -> same kvp layout as before
            if (c16 < 8 && q4 < 2) {
                #pragma unroll
                for (int r = 0; r < 4; ++r)
                    kvp[w][wvid * 64 + (q4 * 4 + r) * 8 + c16] = kvacc[r];
            }
        }

        __syncthreads();  // S3: kvp + tp visible; qk buffers dead -> restage allowed

        // ---- phase C: final kv reduce (128 lanes) overlapped with next head's MFMA ----
        if (n < 64) {
            kv_s[0][n] = (kvp[0][n] + kvp[0][64 + n]) + (kvp[0][128 + n] + kvp[0][192 + n]);
        } else if (n < 128) {
            const int m = n - 64;
            kv_s[1][m] = (kvp[1][m] + kvp[1][64 + m]) + (kvp[1][128 + m] + kvp[1][192 + m]);
        }

        if (h < 7) {
            mfma_stage(0, h + 1);
            mfma_stage(1, h + 1);
        }

        __syncthreads();  // S4: kv_s + next head's projections visible

        // ---- phase D (x2): z, feat, out ----
        #pragma unroll
        for (int w = 0; w < 2; ++w) {
            const float T  = ((tp[w][h & 1][0] + tp[w][h & 1][1]) +
                              (tp[w][h & 1][2] + tp[w][h & 1][3])) + 8.0f * 1e-6f;
            const float zi = 1.0f / (Sq[w] * T);

            float ft[8];
            #pragma unroll
            for (int d = 0; d < 8; ++d) ft[d] = 0.f;
            #pragma unroll
            for (int d = 0; d < 8; ++d) {
                const float qd = qf[w][d];
                const float4 a  = ((const float4*)(kv_s[w] + d * 8))[0];
                const float4 bb = ((const float4*)(kv_s[w] + d * 8))[1];
                ft[0] = fmaf(qd, a.x,  ft[0]);
                ft[1] = fmaf(qd, a.y,  ft[1]);
                ft[2] = fmaf(qd, a.z,  ft[2]);
                ft[3] = fmaf(qd, a.w,  ft[3]);
                ft[4] = fmaf(qd, bb.x, ft[4]);
                ft[5] = fmaf(qd, bb.y, ft[5]);
                ft[6] = fmaf(qd, bb.z, ft[6]);
                ft[7] = fmaf(qd, bb.w, ft[7]);
            }
            #pragma unroll
            for (int d = 0; d < 8; ++d) {
                feat[w][d] = ft[d] * zi;
                out[base[w] + (h * 8 + d) * HW] = feat[w][d];
            }
        }
    }
}

extern "C" void kernel_launch(void* const* d_in, const int* in_sizes, int n_in,
                              void* d_out, int out_size, void* d_ws, size_t ws_size,
                              hipStream_t stream) {
    const float* x  = (const float*)d_in[0];
    const float* w  = (const float*)d_in[1];
    float* out      = (float*)d_out;
    bf16* wh = (bf16*)d_ws;
    bf16* wl = wh + WN;
    wcvt_kernel<<<dim3((WN + 255) / 256), dim3(256), 0, stream>>>(w, wh, wl);
    lwmsa_kernel<<<dim3(2048), dim3(256), 0, stream>>>(x, wh, wl, out);
}